// Round 13
// baseline (118.819 us; speedup 1.0000x reference)
//
#include <hip/hip_runtime.h>
#include <stdint.h>

typedef __bf16 bf16x8 __attribute__((ext_vector_type(8)));
typedef uint16_t u16x8 __attribute__((ext_vector_type(8)));
typedef uint16_t u16x4 __attribute__((ext_vector_type(4)));
typedef float f32x4 __attribute__((ext_vector_type(4)));

#define DEV static __device__ __forceinline__

DEV uint16_t f2bf(float f) {
  union { float f; uint32_t u; } v; v.f = f;
  return (uint16_t)((v.u + 0x8000u) >> 16);
}

#define GLOAD_LDS16(g, l)                                                     \
  __builtin_amdgcn_global_load_lds(                                           \
      (__attribute__((address_space(1))) void*)(g),                           \
      (__attribute__((address_space(3))) void*)(l), 16, 0, 0)

// ---------------- fused prep: bf16 weight converts + mod GEMV (one launch) --------
DEV void conv4(const float* __restrict__ src, uint16_t* __restrict__ dst, int n4,
               int tid, int nth) {
  const float4* s4 = (const float4*)src;
  for (int i = tid; i < n4; i += nth) {
    float4 v = s4[i];
    u16x4 o;
    o[0] = f2bf(v.x); o[1] = f2bf(v.y); o[2] = f2bf(v.z); o[3] = f2bf(v.w);
    *reinterpret_cast<u16x4*>(dst + (size_t)i * 4) = o;
  }
}

__global__ __launch_bounds__(256) void k_prep(
    const float* __restrict__ qkv_w, uint16_t* __restrict__ qkvw_bf,
    const float* __restrict__ out_w, uint16_t* __restrict__ outw_bf,
    const float* __restrict__ cond, const float* __restrict__ ada_w,
    const float* __restrict__ ada_b, float* __restrict__ mod) {
  int blk = blockIdx.x, t = threadIdx.x;
  if (blk < 3072) {  // mod = silu(cond) @ ada_w^T + ada_b (4 x 3072)
    int w = t >> 6, lane = t & 63;
    int gid = blk * 4 + w;
    int b = gid / 3072, j = gid - b * 3072;
    const float* cw = cond + b * 1024;
    const float* aw = ada_w + (size_t)j * 1024;
    float sum = 0.f;
    for (int i = 0; i < 16; ++i) {
      int f = lane + (i << 6);
      float c = cw[f];
      sum += (c / (1.f + __expf(-c))) * aw[f];
    }
    for (int m = 32; m; m >>= 1) sum += __shfl_xor(sum, m, 64);
    if (lane == 0) mod[b * 3072 + j] = sum + ada_b[j];
  } else if (blk < 3072 + 768) {  // qkv_w: 3M elems = 786432 float4
    conv4(qkv_w, qkvw_bf, 786432, (blk - 3072) * 256 + t, 768 * 256);
  } else {  // out_w: 1M elems = 262144 float4
    conv4(out_w, outw_bf, 262144, (blk - 3840) * 256 + t, 256 * 256);
  }
}

// ---------------- RMSNorm + modulate -> xm bf16 (4096 x 1024), float4-vectorized --
__global__ void k_norm_mod(const float* __restrict__ x, const float* __restrict__ norm_scale,
                           const float* __restrict__ mod, uint16_t* __restrict__ xm) {
  int row = blockIdx.x;
  int b = row >> 10;
  int t = threadIdx.x;
  const float4* xr4 = (const float4*)(x + (size_t)row * 1024);
  const float4* ns4 = (const float4*)norm_scale;
  const float4* sh4 = (const float4*)(mod + b * 3072);
  const float4* sc4 = (const float4*)(mod + b * 3072 + 1024);
  float4 v = xr4[t];
  float s = v.x * v.x + v.y * v.y + v.z * v.z + v.w * v.w;
  for (int m = 32; m; m >>= 1) s += __shfl_xor(s, m, 64);
  __shared__ float red[4];
  if ((t & 63) == 0) red[t >> 6] = s;
  __syncthreads();
  s = red[0] + red[1] + red[2] + red[3];
  float inv = rsqrtf(s * (1.f / 1024.f) + 1e-6f);
  float4 ns = ns4[t], sh = sh4[t], sc = sc4[t];
  u16x4 o;
  o[0] = f2bf(v.x * inv * ns.x * (1.f + sc.x) + sh.x);
  o[1] = f2bf(v.y * inv * ns.y * (1.f + sc.y) + sh.y);
  o[2] = f2bf(v.z * inv * ns.z * (1.f + sc.z) + sh.z);
  o[3] = f2bf(v.w * inv * ns.w * (1.f + sc.w) + sh.w);
  *reinterpret_cast<u16x4*>(xm + (size_t)row * 1024 + t * 4) = o;
}

// ---------------- QKV GEMM: 128x128 r4 structure (proven config) ----------------
__global__ __launch_bounds__(256) void k_gemmqkv(const uint16_t* __restrict__ A,
                                                 const uint16_t* __restrict__ B,
                                                 uint16_t* __restrict__ Cbf) {
  constexpr int K = 1024;
  constexpr int N = 3072;
  __shared__ uint16_t As[128 * 32];
  __shared__ uint16_t Bs[128 * 32];
  int t = threadIdx.x;
  int lane = t & 63;
  int w = t >> 6, wr = w >> 1, wc = w & 1;
  int bm = blockIdx.y, bn = blockIdx.x;
  f32x4 acc[4][4] = {};
  const size_t a_base = (size_t)(bm * 128) * K;
  const size_t b_base = (size_t)(bn * 128) * K;
  int r = t >> 2, cch = t & 3;
  for (int kt = 0; kt < K / 32; ++kt) {
    __syncthreads();
#pragma unroll
    for (int i = 0; i < 2; ++i) {
      int rr = r + (i << 6);
      int cs = (cch ^ ((rr >> 1) & 3)) << 3;
      GLOAD_LDS16(A + a_base + (size_t)rr * K + kt * 32 + cs, As + rr * 32 + (cch << 3));
      GLOAD_LDS16(B + b_base + (size_t)rr * K + kt * 32 + cs, Bs + rr * 32 + (cch << 3));
    }
    __syncthreads();
    bf16x8 af[4], bfr[4];
    int lq = lane >> 4;
#pragma unroll
    for (int m = 0; m < 4; ++m) {
      int R = wr * 64 + m * 16 + (lane & 15);
      af[m] = *reinterpret_cast<const bf16x8*>(&As[R * 32 + ((lq ^ ((R >> 1) & 3)) << 3)]);
    }
#pragma unroll
    for (int n = 0; n < 4; ++n) {
      int R = wc * 64 + n * 16 + (lane & 15);
      bfr[n] = *reinterpret_cast<const bf16x8*>(&Bs[R * 32 + ((lq ^ ((R >> 1) & 3)) << 3)]);
    }
#pragma unroll
    for (int m = 0; m < 4; ++m)
#pragma unroll
      for (int n = 0; n < 4; ++n)
        acc[m][n] = __builtin_amdgcn_mfma_f32_16x16x32_bf16(af[m], bfr[n], acc[m][n], 0, 0, 0);
  }
  int row0 = bm * 128 + wr * 64;
  int col0 = bn * 128 + wc * 64;
#pragma unroll
  for (int m = 0; m < 4; ++m)
#pragma unroll
    for (int n = 0; n < 4; ++n)
#pragma unroll
      for (int rr = 0; rr < 4; ++rr) {
        int R = row0 + m * 16 + ((lane >> 4) << 2) + rr;
        int C = col0 + n * 16 + (lane & 15);
        Cbf[(size_t)R * N + C] = f2bf(acc[m][n][rr]);
      }
}

// ---------------- out GEMM: 128(M)x64(N) tile -> 512 blocks = 2/CU ----------------
__global__ __launch_bounds__(256) void k_gemmout(const uint16_t* __restrict__ A,
                                                 const uint16_t* __restrict__ B,
                                                 const float* __restrict__ skip,
                                                 const float* __restrict__ modp,
                                                 float* __restrict__ Cout) {
  constexpr int K = 1024;
  constexpr int N = 1024;
  __shared__ uint16_t As[128 * 32];
  __shared__ uint16_t Bs[64 * 32];
  int t = threadIdx.x;
  int lane = t & 63;
  int w = t >> 6;  // 0..3, M-slice of 32 rows
  int bm = blockIdx.y, bn = blockIdx.x;
  f32x4 acc[2][4] = {};
  const size_t a_base = (size_t)(bm * 128) * K;
  const size_t b_base = (size_t)(bn * 64) * K;
  int r = t >> 2, cch = t & 3;
  for (int kt = 0; kt < K / 32; ++kt) {
    __syncthreads();
#pragma unroll
    for (int i = 0; i < 2; ++i) {
      int rr = r + (i << 6);
      int cs = (cch ^ ((rr >> 1) & 3)) << 3;
      GLOAD_LDS16(A + a_base + (size_t)rr * K + kt * 32 + cs, As + rr * 32 + (cch << 3));
    }
    {
      int rr = r;  // 0..63
      int cs = (cch ^ ((rr >> 1) & 3)) << 3;
      GLOAD_LDS16(B + b_base + (size_t)rr * K + kt * 32 + cs, Bs + rr * 32 + (cch << 3));
    }
    __syncthreads();
    bf16x8 af[2], bfr[4];
    int lq = lane >> 4;
#pragma unroll
    for (int m = 0; m < 2; ++m) {
      int R = w * 32 + m * 16 + (lane & 15);
      af[m] = *reinterpret_cast<const bf16x8*>(&As[R * 32 + ((lq ^ ((R >> 1) & 3)) << 3)]);
    }
#pragma unroll
    for (int n = 0; n < 4; ++n) {
      int R = n * 16 + (lane & 15);
      bfr[n] = *reinterpret_cast<const bf16x8*>(&Bs[R * 32 + ((lq ^ ((R >> 1) & 3)) << 3)]);
    }
#pragma unroll
    for (int m = 0; m < 2; ++m)
#pragma unroll
      for (int n = 0; n < 4; ++n)
        acc[m][n] = __builtin_amdgcn_mfma_f32_16x16x32_bf16(af[m], bfr[n], acc[m][n], 0, 0, 0);
  }
  int row0 = bm * 128 + w * 32;
  int col0 = bn * 64;
#pragma unroll
  for (int m = 0; m < 2; ++m)
#pragma unroll
    for (int n = 0; n < 4; ++n)
#pragma unroll
      for (int rr = 0; rr < 4; ++rr) {
        int R = row0 + m * 16 + ((lane >> 4) << 2) + rr;
        int C = col0 + n * 16 + (lane & 15);
        float g = modp[(R >> 10) * 3072 + 2048 + C];
        Cout[(size_t)R * N + C] = skip[(size_t)R * N + C] + g * acc[m][n][rr];
      }
}

// ---------------- q/k cosine-norm + RoPE + attention layouts ----------------
// Q additionally scaled by log2(e) so attn can use exp2.
__global__ __launch_bounds__(256) void k_qkvpost(
    const uint16_t* __restrict__ qkv, const float* __restrict__ pos,
    const float* __restrict__ freqs, const float* __restrict__ attn_scale,
    uint16_t* __restrict__ Qb, uint16_t* __restrict__ Kb, uint16_t* __restrict__ Vt) {
  __shared__ uint16_t vtile[64 * 66];
  int t = threadIdx.x;
  int st = blockIdx.x, bh = blockIdx.y;
  int b = bh >> 4, h = bh & 15;
  int r = t >> 2;
  int s = t & 3;
  int sp = st * 64 + r;
  size_t m = (size_t)b * 1024 + sp;
  const uint16_t* basep = qkv + m * 3072 + h * 64 + s * 16;
  bf16x8 q0 = *reinterpret_cast<const bf16x8*>(basep);
  bf16x8 q1 = *reinterpret_cast<const bf16x8*>(basep + 8);
  bf16x8 k0 = *reinterpret_cast<const bf16x8*>(basep + 1024);
  bf16x8 k1 = *reinterpret_cast<const bf16x8*>(basep + 1032);
  u16x8 v0 = *reinterpret_cast<const u16x8*>(basep + 2048);
  u16x8 v1 = *reinterpret_cast<const u16x8*>(basep + 2056);
  float qv[16], kv[16];
#pragma unroll
  for (int i = 0; i < 8; ++i) {
    qv[i] = (float)q0[i]; qv[8 + i] = (float)q1[i];
    kv[i] = (float)k0[i]; kv[8 + i] = (float)k1[i];
  }
  float sq = 0.f, sk = 0.f;
#pragma unroll
  for (int i = 0; i < 16; ++i) { sq += qv[i] * qv[i]; sk += kv[i] * kv[i]; }
  sq += __shfl_xor(sq, 1, 64); sq += __shfl_xor(sq, 2, 64);
  sk += __shfl_xor(sk, 1, 64); sk += __shfl_xor(sk, 2, 64);
  float ss = sqrtf(attn_scale[h]);
  float qs = ss * 1.4426950408889634f * rsqrtf(sq + 1e-6f);  // fold log2(e) into Q
  float ks = ss * rsqrtf(sk + 1e-6f);
#pragma unroll
  for (int i = 0; i < 16; ++i) { qv[i] *= qs; kv[i] *= ks; }
  float p0 = pos[m * 2], p1 = pos[m * 2 + 1];
  float sgn = (s == 0) ? -1.f : 1.f;
#pragma unroll
  for (int i = 0; i < 16; ++i) {
    float pq = __shfl_xor(qv[i], 1, 64);
    float pk = __shfl_xor(kv[i], 1, 64);
    if (s < 2) {
      float th = ((i < 8) ? p0 : p1) * freqs[h * 8 + (i & 7)];
      float sn, cs;
      __sincosf(th, &sn, &cs);
      qv[i] = qv[i] * cs + sgn * pq * sn;
      kv[i] = kv[i] * cs + sgn * pk * sn;
    }
  }
  bf16x8 qo0, qo1, ko0, ko1;
#pragma unroll
  for (int i = 0; i < 8; ++i) {
    qo0[i] = (__bf16)qv[i]; qo1[i] = (__bf16)qv[8 + i];
    ko0[i] = (__bf16)kv[i]; ko1[i] = (__bf16)kv[8 + i];
  }
  size_t qkb = ((size_t)bh * 1024 + sp) * 64 + s * 16;
  *reinterpret_cast<bf16x8*>(Qb + qkb) = qo0;
  *reinterpret_cast<bf16x8*>(Qb + qkb + 8) = qo1;
  *reinterpret_cast<bf16x8*>(Kb + qkb) = ko0;
  *reinterpret_cast<bf16x8*>(Kb + qkb + 8) = ko1;
#pragma unroll
  for (int i = 0; i < 8; ++i) {
    vtile[(s * 16 + i) * 66 + r] = v0[i];
    vtile[(s * 16 + 8 + i) * 66 + r] = v1[i];
  }
  __syncthreads();
  int d = t >> 2, c = t & 3;
  u16x8 w0, w1;
#pragma unroll
  for (int i = 0; i < 8; ++i) {
    w0[i] = vtile[d * 66 + c * 16 + i];
    w1[i] = vtile[d * 66 + c * 16 + 8 + i];
  }
  size_t vb = ((size_t)bh * 64 + d) * 1024 + st * 64 + c * 16;
  *reinterpret_cast<u16x8*>(Vt + vb) = w0;
  *reinterpret_cast<u16x8*>(Vt + vb + 8) = w1;
}

// ---------------- flash attention: swapped QK^T (T12-lite) ----------------
// mfma(K,Q) -> lane holds P[q=lane&15][keys 16n+4g+rr] (operand loads identical
// to the unswapped form; only output interpretation changes). Key-adjacent P
// pairs are lane-local -> v_cvt_pk_bf16_f32 + 8 ds_write_b32 replace 32 bit-ops
// + 16 ds_write_b16. Denominator: per-lane scalar partial (q=lane&15), one
// cross-g reduce + 4 shfl redistribution at the end. PV path unchanged.
__global__ __launch_bounds__(512) void k_attn(const uint16_t* __restrict__ Qb,
                                              const uint16_t* __restrict__ Kb,
                                              const uint16_t* __restrict__ Vt,
                                              uint16_t* __restrict__ obuf) {
  __shared__ uint16_t Ks[64 * 64];
  __shared__ uint16_t Vs[64 * 64];
  __shared__ uint16_t Ps[8][16 * 88];
  int t = threadIdx.x, lane = t & 63, w = t >> 6;
  int qt = blockIdx.y, bh = blockIdx.x;
  int b = bh >> 4, h = bh & 15;
  int qrow = qt * 128 + w * 16 + (lane & 15);
  int klo = (lane >> 4) << 3;
  int g = lane >> 4;
  const uint16_t* qptr = Qb + ((size_t)bh * 1024 + qrow) * 64 + klo;
  bf16x8 qf0 = *reinterpret_cast<const bf16x8*>(qptr);
  bf16x8 qf1 = *reinterpret_cast<const bf16x8*>(qptr + 32);
  f32x4 oacc[4] = {};
  float dsum = 0.f;  // partial denom for q = lane&15
  // packed P write base: row q=lane&15, col 4g (u32-aligned: 88 and 4g even)
  uint32_t* pw32 = reinterpret_cast<uint32_t*>(&Ps[w][(lane & 15) * 88 + (g << 2)]);
  const uint16_t* pr = &Ps[w][(lane & 15) * 88];
  const size_t kbase = (size_t)bh * 1024 * 64;
  const size_t vbase = (size_t)bh * 64 * 1024;
  for (int kt = 0; kt < 16; ++kt) {
    __syncthreads();
    {
      int row = t >> 3;
      int ce = ((t & 7) ^ (row & 7)) << 3;
      GLOAD_LDS16(Kb + kbase + (size_t)(kt * 64 + row) * 64 + ce, Ks + t * 8);
      GLOAD_LDS16(Vt + vbase + (size_t)row * 1024 + kt * 64 + ce, Vs + t * 8);
    }
    __syncthreads();
#pragma unroll
    for (int n = 0; n < 4; ++n) {
      int row = n * 16 + (lane & 15);
      int sw = (row & 7) << 3;
      bf16x8 kf0 = *reinterpret_cast<const bf16x8*>(&Ks[row * 64 + (klo ^ sw)]);
      bf16x8 kf1 = *reinterpret_cast<const bf16x8*>(&Ks[row * 64 + ((32 + klo) ^ sw)]);
      f32x4 z = {};
      z = __builtin_amdgcn_mfma_f32_16x16x32_bf16(kf0, qf0, z, 0, 0, 0);  // swapped
      z = __builtin_amdgcn_mfma_f32_16x16x32_bf16(kf1, qf1, z, 0, 0, 0);
      float p0 = exp2f(z[0]), p1 = exp2f(z[1]), p2 = exp2f(z[2]), p3 = exp2f(z[3]);
      dsum += (p0 + p1) + (p2 + p3);
      uint32_t w0, w1;
      asm("v_cvt_pk_bf16_f32 %0, %1, %2" : "=v"(w0) : "v"(p0), "v"(p1));
      asm("v_cvt_pk_bf16_f32 %0, %1, %2" : "=v"(w1) : "v"(p2), "v"(p3));
      pw32[8 * n] = w0;      // keys 16n+4g+0,1
      pw32[8 * n + 1] = w1;  // keys 16n+4g+2,3
    }
    bf16x8 pa0 = *reinterpret_cast<const bf16x8*>(pr + klo);
    bf16x8 pa1 = *reinterpret_cast<const bf16x8*>(pr + 32 + klo);
#pragma unroll
    for (int dt = 0; dt < 4; ++dt) {
      int row = dt * 16 + (lane & 15);
      int sw = (row & 7) << 3;
      bf16x8 vf0 = *reinterpret_cast<const bf16x8*>(&Vs[row * 64 + (klo ^ sw)]);
      bf16x8 vf1 = *reinterpret_cast<const bf16x8*>(&Vs[row * 64 + ((32 + klo) ^ sw)]);
      oacc[dt] = __builtin_amdgcn_mfma_f32_16x16x32_bf16(pa0, vf0, oacc[dt], 0, 0, 0);
      oacc[dt] = __builtin_amdgcn_mfma_f32_16x16x32_bf16(pa1, vf1, oacc[dt], 0, 0, 0);
    }
  }
  // full denom for q=lane&15, then redistribute to output rows q=(g<<2)+rr
  dsum += __shfl_xor(dsum, 16, 64);
  dsum += __shfl_xor(dsum, 32, 64);
#pragma unroll
  for (int rr = 0; rr < 4; ++rr) {
    float rinv = 1.f / __shfl(dsum, (g << 2) + rr, 64);
    int sp = qt * 128 + w * 16 + (g << 2) + rr;
    size_t orow = ((size_t)b * 1024 + sp) * 1024 + h * 64;
#pragma unroll
    for (int dt = 0; dt < 4; ++dt)
      obuf[orow + dt * 16 + (lane & 15)] = f2bf(oacc[dt][rr] * rinv);
  }
}

extern "C" void kernel_launch(void* const* d_in, const int* in_sizes, int n_in,
                              void* d_out, int out_size, void* d_ws, size_t ws_size,
                              hipStream_t stream) {
  const float* x = (const float*)d_in[0];
  const float* pos = (const float*)d_in[1];
  const float* cond = (const float*)d_in[2];
  const float* norm_scale = (const float*)d_in[3];
  const float* ada_w = (const float*)d_in[4];
  const float* ada_b = (const float*)d_in[5];
  const float* qkv_w = (const float*)d_in[6];
  const float* attn_scale = (const float*)d_in[7];
  const float* out_w = (const float*)d_in[8];
  const float* freqs = (const float*)d_in[9];
  float* out = (float*)d_out;
  char* ws = (char*)d_ws;
  float* mod = (float*)(ws + 0);                  //  49,152
  uint16_t* xm = (uint16_t*)(ws + 65536);         //   8 MB
  uint16_t* qkvw_bf = (uint16_t*)(ws + 8454144);  //   6 MB
  uint16_t* outw_bf = (uint16_t*)(ws + 14745600); //   2 MB
  uint16_t* qkv = (uint16_t*)(ws + 16842752);     //  24 MB
  uint16_t* Qb = (uint16_t*)(ws + 42008576);      //   8 MB
  uint16_t* Kb = (uint16_t*)(ws + 50397184);      //   8 MB
  uint16_t* Vt = (uint16_t*)(ws + 58785792);      //   8 MB
  uint16_t* obuf = (uint16_t*)(ws + 67174400);    //   8 MB

  k_prep<<<dim3(4096), dim3(256), 0, stream>>>(qkv_w, qkvw_bf, out_w, outw_bf,
                                               cond, ada_w, ada_b, mod);
  k_norm_mod<<<dim3(4096), dim3(256), 0, stream>>>(x, norm_scale, mod, xm);
  k_gemmqkv<<<dim3(24, 32), dim3(256), 0, stream>>>(xm, qkvw_bf, qkv);
  k_qkvpost<<<dim3(16, 64), dim3(256), 0, stream>>>(qkv, pos, freqs, attn_scale, Qb, Kb, Vt);
  k_attn<<<dim3(64, 8), dim3(512), 0, stream>>>(Qb, Kb, Vt, obuf);
  k_gemmout<<<dim3(16, 32), dim3(256), 0, stream>>>(obuf, outw_bf, x, mod, out);
}

// Round 14
// 118.290 us; speedup vs baseline: 1.0045x; 1.0045x over previous
//
#include <hip/hip_runtime.h>
#include <stdint.h>

typedef __bf16 bf16x8 __attribute__((ext_vector_type(8)));
typedef uint16_t u16x8 __attribute__((ext_vector_type(8)));
typedef uint16_t u16x4 __attribute__((ext_vector_type(4)));
typedef float f32x4 __attribute__((ext_vector_type(4)));

#define DEV static __device__ __forceinline__

DEV uint16_t f2bf(float f) {
  union { float f; uint32_t u; } v; v.f = f;
  return (uint16_t)((v.u + 0x8000u) >> 16);
}

#define GLOAD_LDS16(g, l)                                                     \
  __builtin_amdgcn_global_load_lds(                                           \
      (__attribute__((address_space(1))) void*)(g),                           \
      (__attribute__((address_space(3))) void*)(l), 16, 0, 0)

// ---------------- fused prep: bf16 weight converts + mod GEMV (one launch) --------
DEV void conv4(const float* __restrict__ src, uint16_t* __restrict__ dst, int n4,
               int tid, int nth) {
  const float4* s4 = (const float4*)src;
  for (int i = tid; i < n4; i += nth) {
    float4 v = s4[i];
    u16x4 o;
    o[0] = f2bf(v.x); o[1] = f2bf(v.y); o[2] = f2bf(v.z); o[3] = f2bf(v.w);
    *reinterpret_cast<u16x4*>(dst + (size_t)i * 4) = o;
  }
}

__global__ __launch_bounds__(256) void k_prep(
    const float* __restrict__ qkv_w, uint16_t* __restrict__ qkvw_bf,
    const float* __restrict__ out_w, uint16_t* __restrict__ outw_bf,
    const float* __restrict__ cond, const float* __restrict__ ada_w,
    const float* __restrict__ ada_b, float* __restrict__ mod) {
  int blk = blockIdx.x, t = threadIdx.x;
  if (blk < 3072) {  // mod = silu(cond) @ ada_w^T + ada_b (4 x 3072)
    int w = t >> 6, lane = t & 63;
    int gid = blk * 4 + w;
    int b = gid / 3072, j = gid - b * 3072;
    const float* cw = cond + b * 1024;
    const float* aw = ada_w + (size_t)j * 1024;
    float sum = 0.f;
    for (int i = 0; i < 16; ++i) {
      int f = lane + (i << 6);
      float c = cw[f];
      sum += (c / (1.f + __expf(-c))) * aw[f];
    }
    for (int m = 32; m; m >>= 1) sum += __shfl_xor(sum, m, 64);
    if (lane == 0) mod[b * 3072 + j] = sum + ada_b[j];
  } else if (blk < 3072 + 768) {  // qkv_w: 3M elems = 786432 float4
    conv4(qkv_w, qkvw_bf, 786432, (blk - 3072) * 256 + t, 768 * 256);
  } else {  // out_w: 1M elems = 262144 float4
    conv4(out_w, outw_bf, 262144, (blk - 3840) * 256 + t, 256 * 256);
  }
}

// ---------------- RMSNorm + modulate -> xm bf16 (4096 x 1024), float4-vectorized --
__global__ void k_norm_mod(const float* __restrict__ x, const float* __restrict__ norm_scale,
                           const float* __restrict__ mod, uint16_t* __restrict__ xm) {
  int row = blockIdx.x;
  int b = row >> 10;
  int t = threadIdx.x;
  const float4* xr4 = (const float4*)(x + (size_t)row * 1024);
  const float4* ns4 = (const float4*)norm_scale;
  const float4* sh4 = (const float4*)(mod + b * 3072);
  const float4* sc4 = (const float4*)(mod + b * 3072 + 1024);
  float4 v = xr4[t];
  float s = v.x * v.x + v.y * v.y + v.z * v.z + v.w * v.w;
  for (int m = 32; m; m >>= 1) s += __shfl_xor(s, m, 64);
  __shared__ float red[4];
  if ((t & 63) == 0) red[t >> 6] = s;
  __syncthreads();
  s = red[0] + red[1] + red[2] + red[3];
  float inv = rsqrtf(s * (1.f / 1024.f) + 1e-6f);
  float4 ns = ns4[t], sh = sh4[t], sc = sc4[t];
  u16x4 o;
  o[0] = f2bf(v.x * inv * ns.x * (1.f + sc.x) + sh.x);
  o[1] = f2bf(v.y * inv * ns.y * (1.f + sc.y) + sh.y);
  o[2] = f2bf(v.z * inv * ns.z * (1.f + sc.z) + sh.z);
  o[3] = f2bf(v.w * inv * ns.w * (1.f + sc.w) + sh.w);
  *reinterpret_cast<u16x4*>(xm + (size_t)row * 1024 + t * 4) = o;
}

// ---------------- QKV GEMM: 128x128 r4 structure (proven config) ----------------
__global__ __launch_bounds__(256) void k_gemmqkv(const uint16_t* __restrict__ A,
                                                 const uint16_t* __restrict__ B,
                                                 uint16_t* __restrict__ Cbf) {
  constexpr int K = 1024;
  constexpr int N = 3072;
  __shared__ uint16_t As[128 * 32];
  __shared__ uint16_t Bs[128 * 32];
  int t = threadIdx.x;
  int lane = t & 63;
  int w = t >> 6, wr = w >> 1, wc = w & 1;
  int bm = blockIdx.y, bn = blockIdx.x;
  f32x4 acc[4][4] = {};
  const size_t a_base = (size_t)(bm * 128) * K;
  const size_t b_base = (size_t)(bn * 128) * K;
  int r = t >> 2, cch = t & 3;
  for (int kt = 0; kt < K / 32; ++kt) {
    __syncthreads();
#pragma unroll
    for (int i = 0; i < 2; ++i) {
      int rr = r + (i << 6);
      int cs = (cch ^ ((rr >> 1) & 3)) << 3;
      GLOAD_LDS16(A + a_base + (size_t)rr * K + kt * 32 + cs, As + rr * 32 + (cch << 3));
      GLOAD_LDS16(B + b_base + (size_t)rr * K + kt * 32 + cs, Bs + rr * 32 + (cch << 3));
    }
    __syncthreads();
    bf16x8 af[4], bfr[4];
    int lq = lane >> 4;
#pragma unroll
    for (int m = 0; m < 4; ++m) {
      int R = wr * 64 + m * 16 + (lane & 15);
      af[m] = *reinterpret_cast<const bf16x8*>(&As[R * 32 + ((lq ^ ((R >> 1) & 3)) << 3)]);
    }
#pragma unroll
    for (int n = 0; n < 4; ++n) {
      int R = wc * 64 + n * 16 + (lane & 15);
      bfr[n] = *reinterpret_cast<const bf16x8*>(&Bs[R * 32 + ((lq ^ ((R >> 1) & 3)) << 3)]);
    }
#pragma unroll
    for (int m = 0; m < 4; ++m)
#pragma unroll
      for (int n = 0; n < 4; ++n)
        acc[m][n] = __builtin_amdgcn_mfma_f32_16x16x32_bf16(af[m], bfr[n], acc[m][n], 0, 0, 0);
  }
  int row0 = bm * 128 + wr * 64;
  int col0 = bn * 128 + wc * 64;
#pragma unroll
  for (int m = 0; m < 4; ++m)
#pragma unroll
    for (int n = 0; n < 4; ++n)
#pragma unroll
      for (int rr = 0; rr < 4; ++rr) {
        int R = row0 + m * 16 + ((lane >> 4) << 2) + rr;
        int C = col0 + n * 16 + (lane & 15);
        Cbf[(size_t)R * N + C] = f2bf(acc[m][n][rr]);
      }
}

// ---------------- out GEMM: 128(M)x64(N) tile -> 512 blocks = 2/CU ----------------
__global__ __launch_bounds__(256) void k_gemmout(const uint16_t* __restrict__ A,
                                                 const uint16_t* __restrict__ B,
                                                 const float* __restrict__ skip,
                                                 const float* __restrict__ modp,
                                                 float* __restrict__ Cout) {
  constexpr int K = 1024;
  constexpr int N = 1024;
  __shared__ uint16_t As[128 * 32];
  __shared__ uint16_t Bs[64 * 32];
  int t = threadIdx.x;
  int lane = t & 63;
  int w = t >> 6;  // 0..3, M-slice of 32 rows
  int bm = blockIdx.y, bn = blockIdx.x;
  f32x4 acc[2][4] = {};
  const size_t a_base = (size_t)(bm * 128) * K;
  const size_t b_base = (size_t)(bn * 64) * K;
  int r = t >> 2, cch = t & 3;
  for (int kt = 0; kt < K / 32; ++kt) {
    __syncthreads();
#pragma unroll
    for (int i = 0; i < 2; ++i) {
      int rr = r + (i << 6);
      int cs = (cch ^ ((rr >> 1) & 3)) << 3;
      GLOAD_LDS16(A + a_base + (size_t)rr * K + kt * 32 + cs, As + rr * 32 + (cch << 3));
    }
    {
      int rr = r;  // 0..63
      int cs = (cch ^ ((rr >> 1) & 3)) << 3;
      GLOAD_LDS16(B + b_base + (size_t)rr * K + kt * 32 + cs, Bs + rr * 32 + (cch << 3));
    }
    __syncthreads();
    bf16x8 af[2], bfr[4];
    int lq = lane >> 4;
#pragma unroll
    for (int m = 0; m < 2; ++m) {
      int R = w * 32 + m * 16 + (lane & 15);
      af[m] = *reinterpret_cast<const bf16x8*>(&As[R * 32 + ((lq ^ ((R >> 1) & 3)) << 3)]);
    }
#pragma unroll
    for (int n = 0; n < 4; ++n) {
      int R = n * 16 + (lane & 15);
      bfr[n] = *reinterpret_cast<const bf16x8*>(&Bs[R * 32 + ((lq ^ ((R >> 1) & 3)) << 3)]);
    }
#pragma unroll
    for (int m = 0; m < 2; ++m)
#pragma unroll
      for (int n = 0; n < 4; ++n)
        acc[m][n] = __builtin_amdgcn_mfma_f32_16x16x32_bf16(af[m], bfr[n], acc[m][n], 0, 0, 0);
  }
  int row0 = bm * 128 + w * 32;
  int col0 = bn * 64;
#pragma unroll
  for (int m = 0; m < 2; ++m)
#pragma unroll
    for (int n = 0; n < 4; ++n)
#pragma unroll
      for (int rr = 0; rr < 4; ++rr) {
        int R = row0 + m * 16 + ((lane >> 4) << 2) + rr;
        int C = col0 + n * 16 + (lane & 15);
        float g = modp[(R >> 10) * 3072 + 2048 + C];
        Cout[(size_t)R * N + C] = skip[(size_t)R * N + C] + g * acc[m][n][rr];
      }
}

// ---------------- q/k cosine-norm + RoPE + attention layouts ----------------
// Q additionally scaled by log2(e) so attn can use exp2.
__global__ __launch_bounds__(256) void k_qkvpost(
    const uint16_t* __restrict__ qkv, const float* __restrict__ pos,
    const float* __restrict__ freqs, const float* __restrict__ attn_scale,
    uint16_t* __restrict__ Qb, uint16_t* __restrict__ Kb, uint16_t* __restrict__ Vt) {
  __shared__ uint16_t vtile[64 * 66];
  int t = threadIdx.x;
  int st = blockIdx.x, bh = blockIdx.y;
  int b = bh >> 4, h = bh & 15;
  int r = t >> 2;
  int s = t & 3;
  int sp = st * 64 + r;
  size_t m = (size_t)b * 1024 + sp;
  const uint16_t* basep = qkv + m * 3072 + h * 64 + s * 16;
  bf16x8 q0 = *reinterpret_cast<const bf16x8*>(basep);
  bf16x8 q1 = *reinterpret_cast<const bf16x8*>(basep + 8);
  bf16x8 k0 = *reinterpret_cast<const bf16x8*>(basep + 1024);
  bf16x8 k1 = *reinterpret_cast<const bf16x8*>(basep + 1032);
  u16x8 v0 = *reinterpret_cast<const u16x8*>(basep + 2048);
  u16x8 v1 = *reinterpret_cast<const u16x8*>(basep + 2056);
  float qv[16], kv[16];
#pragma unroll
  for (int i = 0; i < 8; ++i) {
    qv[i] = (float)q0[i]; qv[8 + i] = (float)q1[i];
    kv[i] = (float)k0[i]; kv[8 + i] = (float)k1[i];
  }
  float sq = 0.f, sk = 0.f;
#pragma unroll
  for (int i = 0; i < 16; ++i) { sq += qv[i] * qv[i]; sk += kv[i] * kv[i]; }
  sq += __shfl_xor(sq, 1, 64); sq += __shfl_xor(sq, 2, 64);
  sk += __shfl_xor(sk, 1, 64); sk += __shfl_xor(sk, 2, 64);
  float ss = sqrtf(attn_scale[h]);
  float qs = ss * 1.4426950408889634f * rsqrtf(sq + 1e-6f);  // fold log2(e) into Q
  float ks = ss * rsqrtf(sk + 1e-6f);
#pragma unroll
  for (int i = 0; i < 16; ++i) { qv[i] *= qs; kv[i] *= ks; }
  float p0 = pos[m * 2], p1 = pos[m * 2 + 1];
  float sgn = (s == 0) ? -1.f : 1.f;
#pragma unroll
  for (int i = 0; i < 16; ++i) {
    float pq = __shfl_xor(qv[i], 1, 64);
    float pk = __shfl_xor(kv[i], 1, 64);
    if (s < 2) {
      float th = ((i < 8) ? p0 : p1) * freqs[h * 8 + (i & 7)];
      float sn, cs;
      __sincosf(th, &sn, &cs);
      qv[i] = qv[i] * cs + sgn * pq * sn;
      kv[i] = kv[i] * cs + sgn * pk * sn;
    }
  }
  bf16x8 qo0, qo1, ko0, ko1;
#pragma unroll
  for (int i = 0; i < 8; ++i) {
    qo0[i] = (__bf16)qv[i]; qo1[i] = (__bf16)qv[8 + i];
    ko0[i] = (__bf16)kv[i]; ko1[i] = (__bf16)kv[8 + i];
  }
  size_t qkb = ((size_t)bh * 1024 + sp) * 64 + s * 16;
  *reinterpret_cast<bf16x8*>(Qb + qkb) = qo0;
  *reinterpret_cast<bf16x8*>(Qb + qkb + 8) = qo1;
  *reinterpret_cast<bf16x8*>(Kb + qkb) = ko0;
  *reinterpret_cast<bf16x8*>(Kb + qkb + 8) = ko1;
#pragma unroll
  for (int i = 0; i < 8; ++i) {
    vtile[(s * 16 + i) * 66 + r] = v0[i];
    vtile[(s * 16 + 8 + i) * 66 + r] = v1[i];
  }
  __syncthreads();
  int d = t >> 2, c = t & 3;
  u16x8 w0, w1;
#pragma unroll
  for (int i = 0; i < 8; ++i) {
    w0[i] = vtile[d * 66 + c * 16 + i];
    w1[i] = vtile[d * 66 + c * 16 + 8 + i];
  }
  size_t vb = ((size_t)bh * 64 + d) * 1024 + st * 64 + c * 16;
  *reinterpret_cast<u16x8*>(Vt + vb) = w0;
  *reinterpret_cast<u16x8*>(Vt + vb + 8) = w1;
}

// ---------------- flash attention: swapped QK^T + K/V LDS double-buffer -----------
// Grid supplies only 2 blocks/CU (512 blocks / 256 CU), so growing LDS to
// 54.6KB for dbuf costs ZERO occupancy (2/CU capacity retained). Stage(kt+1)
// issued BEFORE compute(kt); single __syncthreads per kt (drain happens after
// ~600cy of QK+softmax+PV). Barriers 32 -> 17.
__global__ __launch_bounds__(512) void k_attn(const uint16_t* __restrict__ Qb,
                                              const uint16_t* __restrict__ Kb,
                                              const uint16_t* __restrict__ Vt,
                                              uint16_t* __restrict__ obuf) {
  __shared__ uint16_t Ks[2][64 * 64];
  __shared__ uint16_t Vs[2][64 * 64];
  __shared__ uint16_t Ps[8][16 * 88];
  int t = threadIdx.x, lane = t & 63, w = t >> 6;
  int qt = blockIdx.y, bh = blockIdx.x;
  int b = bh >> 4, h = bh & 15;
  int qrow = qt * 128 + w * 16 + (lane & 15);
  int klo = (lane >> 4) << 3;
  int g = lane >> 4;
  const uint16_t* qptr = Qb + ((size_t)bh * 1024 + qrow) * 64 + klo;
  bf16x8 qf0 = *reinterpret_cast<const bf16x8*>(qptr);
  bf16x8 qf1 = *reinterpret_cast<const bf16x8*>(qptr + 32);
  f32x4 oacc[4] = {};
  float dsum = 0.f;  // partial denom for q = lane&15
  uint32_t* pw32 = reinterpret_cast<uint32_t*>(&Ps[w][(lane & 15) * 88 + (g << 2)]);
  const uint16_t* pr = &Ps[w][(lane & 15) * 88];
  // staging addresses (kt-invariant bases)
  int srow = t >> 3;
  int sce = ((t & 7) ^ (srow & 7)) << 3;
  const uint16_t* kg = Kb + (size_t)bh * 1024 * 64 + (size_t)srow * 64 + sce;
  const uint16_t* vg = Vt + (size_t)bh * 64 * 1024 + (size_t)srow * 1024 + sce;
  // prologue: stage tile 0
  GLOAD_LDS16(kg, &Ks[0][t * 8]);
  GLOAD_LDS16(vg, &Vs[0][t * 8]);
  __syncthreads();
  for (int kt = 0; kt < 16; ++kt) {
    int cur = kt & 1;
    if (kt < 15) {  // stage next tile early; lands during compute, sealed at barrier
      GLOAD_LDS16(kg + (size_t)(kt + 1) * 4096, &Ks[cur ^ 1][t * 8]);
      GLOAD_LDS16(vg + (size_t)(kt + 1) * 64, &Vs[cur ^ 1][t * 8]);
    }
#pragma unroll
    for (int n = 0; n < 4; ++n) {
      int row = n * 16 + (lane & 15);
      int sw = (row & 7) << 3;
      bf16x8 kf0 = *reinterpret_cast<const bf16x8*>(&Ks[cur][row * 64 + (klo ^ sw)]);
      bf16x8 kf1 = *reinterpret_cast<const bf16x8*>(&Ks[cur][row * 64 + ((32 + klo) ^ sw)]);
      f32x4 z = {};
      z = __builtin_amdgcn_mfma_f32_16x16x32_bf16(kf0, qf0, z, 0, 0, 0);  // swapped
      z = __builtin_amdgcn_mfma_f32_16x16x32_bf16(kf1, qf1, z, 0, 0, 0);
      float p0 = exp2f(z[0]), p1 = exp2f(z[1]), p2 = exp2f(z[2]), p3 = exp2f(z[3]);
      dsum += (p0 + p1) + (p2 + p3);
      uint32_t w0, w1;
      asm("v_cvt_pk_bf16_f32 %0, %1, %2" : "=v"(w0) : "v"(p0), "v"(p1));
      asm("v_cvt_pk_bf16_f32 %0, %1, %2" : "=v"(w1) : "v"(p2), "v"(p3));
      pw32[8 * n] = w0;      // keys 16n+4g+0,1
      pw32[8 * n + 1] = w1;  // keys 16n+4g+2,3
    }
    bf16x8 pa0 = *reinterpret_cast<const bf16x8*>(pr + klo);
    bf16x8 pa1 = *reinterpret_cast<const bf16x8*>(pr + 32 + klo);
#pragma unroll
    for (int dt = 0; dt < 4; ++dt) {
      int row = dt * 16 + (lane & 15);
      int sw = (row & 7) << 3;
      bf16x8 vf0 = *reinterpret_cast<const bf16x8*>(&Vs[cur][row * 64 + (klo ^ sw)]);
      bf16x8 vf1 = *reinterpret_cast<const bf16x8*>(&Vs[cur][row * 64 + ((32 + klo) ^ sw)]);
      oacc[dt] = __builtin_amdgcn_mfma_f32_16x16x32_bf16(pa0, vf0, oacc[dt], 0, 0, 0);
      oacc[dt] = __builtin_amdgcn_mfma_f32_16x16x32_bf16(pa1, vf1, oacc[dt], 0, 0, 0);
    }
    __syncthreads();  // seals: next tile landed (vmcnt0), reads of cur done
  }
  // full denom for q=lane&15, then redistribute to output rows q=(g<<2)+rr
  dsum += __shfl_xor(dsum, 16, 64);
  dsum += __shfl_xor(dsum, 32, 64);
#pragma unroll
  for (int rr = 0; rr < 4; ++rr) {
    float rinv = 1.f / __shfl(dsum, (g << 2) + rr, 64);
    int sp = qt * 128 + w * 16 + (g << 2) + rr;
    size_t orow = ((size_t)b * 1024 + sp) * 1024 + h * 64;
#pragma unroll
    for (int dt = 0; dt < 4; ++dt)
      obuf[orow + dt * 16 + (lane & 15)] = f2bf(oacc[dt][rr] * rinv);
  }
}

extern "C" void kernel_launch(void* const* d_in, const int* in_sizes, int n_in,
                              void* d_out, int out_size, void* d_ws, size_t ws_size,
                              hipStream_t stream) {
  const float* x = (const float*)d_in[0];
  const float* pos = (const float*)d_in[1];
  const float* cond = (const float*)d_in[2];
  const float* norm_scale = (const float*)d_in[3];
  const float* ada_w = (const float*)d_in[4];
  const float* ada_b = (const float*)d_in[5];
  const float* qkv_w = (const float*)d_in[6];
  const float* attn_scale = (const float*)d_in[7];
  const float* out_w = (const float*)d_in[8];
  const float* freqs = (const float*)d_in[9];
  float* out = (float*)d_out;
  char* ws = (char*)d_ws;
  float* mod = (float*)(ws + 0);                  //  49,152
  uint16_t* xm = (uint16_t*)(ws + 65536);         //   8 MB
  uint16_t* qkvw_bf = (uint16_t*)(ws + 8454144);  //   6 MB
  uint16_t* outw_bf = (uint16_t*)(ws + 14745600); //   2 MB
  uint16_t* qkv = (uint16_t*)(ws + 16842752);     //  24 MB
  uint16_t* Qb = (uint16_t*)(ws + 42008576);      //   8 MB
  uint16_t* Kb = (uint16_t*)(ws + 50397184);      //   8 MB
  uint16_t* Vt = (uint16_t*)(ws + 58785792);      //   8 MB
  uint16_t* obuf = (uint16_t*)(ws + 67174400);    //   8 MB

  k_prep<<<dim3(4096), dim3(256), 0, stream>>>(qkv_w, qkvw_bf, out_w, outw_bf,
                                               cond, ada_w, ada_b, mod);
  k_norm_mod<<<dim3(4096), dim3(256), 0, stream>>>(x, norm_scale, mod, xm);
  k_gemmqkv<<<dim3(24, 32), dim3(256), 0, stream>>>(xm, qkvw_bf, qkv);
  k_qkvpost<<<dim3(16, 64), dim3(256), 0, stream>>>(qkv, pos, freqs, attn_scale, Qb, Kb, Vt);
  k_attn<<<dim3(64, 8), dim3(512), 0, stream>>>(Qb, Kb, Vt, obuf);
  k_gemmout<<<dim3(16, 32), dim3(256), 0, stream>>>(obuf, outw_bf, x, mod, out);
}